// Round 5
// baseline (593.603 us; speedup 1.0000x reference)
//
#include <hip/hip_runtime.h>

#define NN 100000
#define NE 625000
#define HD 128
#define NT 6250            // 100000/16 row-tiles, exact
#define CAST_N (NN * 32)
#define PREP_N (6 * 16384)

typedef unsigned int u32;
typedef unsigned short u16;
typedef __bf16 bf16x8 __attribute__((ext_vector_type(8)));
typedef float f32x4 __attribute__((ext_vector_type(4)));
typedef float f32x2 __attribute__((ext_vector_type(2)));

__device__ __forceinline__ u16 f2b(float f) {
  u32 u = __float_as_uint(f);
  u32 r = (u + 0x7FFFu + ((u >> 16) & 1u)) >> 16;
  return (u16)r;
}
__device__ __forceinline__ float b2f(u32 u) { return __uint_as_float(u << 16); }

// DPP-fused butterfly step: x + perm(x).  CTRL compile-time const.
template <int CTRL>
__device__ __forceinline__ float dppadd(float x) {
  int t = __builtin_amdgcn_update_dpp(0, __float_as_int(x), CTRL, 0xf, 0xf, true);
  return x + __int_as_float(t);
}

// ---- fused startup: x cast (bf16) + weight transpose/cast + dst histogram ----
__global__ void k_init(const float* __restrict__ x, u16* __restrict__ xb,
                       const float* __restrict__ Wl, const float* __restrict__ Wr,
                       const float* __restrict__ Wlin, u16* __restrict__ Wt,
                       const int* __restrict__ dst, int* __restrict__ deg) {
  int i = blockIdx.x * blockDim.x + threadIdx.x;
  if (i < CAST_N) {
    float4 v = *(const float4*)(x + (size_t)i * 4);
    uint2 o;
    o.x = (u32)f2b(v.x) | ((u32)f2b(v.y) << 16);
    o.y = (u32)f2b(v.z) | ((u32)f2b(v.w) << 16);
    *(uint2*)(xb + (size_t)i * 4) = o;
  } else if (i < CAST_N + PREP_N) {
    int j = i - CAST_N;
    int mat = j >> 14;
    int l = mat / 3, which = mat % 3;
    int rem = j & 16383;
    int hh = rem >> 7, dd = rem & 127;
    const float* src = (which == 0) ? Wl : (which == 1) ? Wr : Wlin;
    float v = src[l * 16384 + dd * 128 + hh];
    if (which == 2 && dd == hh) v += 1.0f;  // fold residual into Wlin
    Wt[l * (3 * 16384) + which * 16384 + hh * 128 + dd] = f2b(v);
  } else {
    int e = i - CAST_N - PREP_N;
    if (e < NE) atomicAdd(&deg[dst[e]], 1);
  }
}

// ---- CSR build ----
__global__ void k_alloc(const int* __restrict__ deg, int* __restrict__ row_start,
                        int* __restrict__ cursor) {
  int idx = blockIdx.x * blockDim.x + threadIdx.x;
  int lane = threadIdx.x & 63;
  int v = (idx < NN) ? deg[idx] : 0;
  int incl = v;
  #pragma unroll
  for (int off = 1; off < 64; off <<= 1) {
    int t = __shfl_up(incl, off, 64);
    if (lane >= off) incl += t;
  }
  int total = __shfl(incl, 63, 64);
  int base = 0;
  if (lane == 63) base = atomicAdd(cursor, total);
  base = __shfl(base, 63, 64);
  if (idx < NN) row_start[idx] = base + incl - v;
}

__global__ void k_fill(const int* __restrict__ src, const int* __restrict__ dst,
                       const int* __restrict__ row_start, int* __restrict__ cnt,
                       int* __restrict__ ss) {
  int e = blockIdx.x * blockDim.x + threadIdx.x;
  if (e >= NE) return;
  int d = dst[e];
  int p = row_start[d] + atomicAdd(&cnt[d], 1);
  ss[p] = src[e];
}

// ---- GEMM v7: BARRIER-FREE. One wave = one 16-row tile. ----
// Diagnosis rounds 3/4: every __syncthreads drains vmcnt(0) for all resident
// waves together -> chip-wide in-flight bytes collapse -> 1.2-2.3 TB/s.
// Fix: B (32KB, L2-resident) is read per-fragment straight from L2 — no LDS
// staging, no block cooperation, ZERO barriers. Each wave: burst-load A frags
// (4x dwordx4, HBM) + B frags (32x b128, L2), 32 MFMAs, bounce through a
// wave-PRIVATE LDS region (no sync: same wave), 4 coalesced uint4 stores.
// 16 waves/CU at uncorrelated phases keep loads continuously in flight.
// Conv: both B passes per wave (A read once). In-place safe for lin
// (o0==A: wave reads its own rows before writing them; rows wave-exclusive).
__global__ __launch_bounds__(256, 4) void k_gemm7(
    const u16* __restrict__ A,
    const u16* __restrict__ Bt0, const u16* __restrict__ Bt1,
    const float* __restrict__ bias0, const float* __restrict__ bias1,
    u16* __restrict__ o0, u16* __restrict__ o1) {
  __shared__ __align__(16) u16 lO[4][16 * 136];  // per-wave bounce
  const int tid = threadIdx.x;
  const int wv = tid >> 6, lane = tid & 63;
  const int colt = lane & 15, kq = lane >> 4;
  const int tile = blockIdx.x * 4 + wv;
  if (tile >= NT) return;
  u16* myO = (u16*)lO[wv];

  const u16* Ab = A + ((size_t)tile * 16 + colt) * HD + kq * 8;

  bf16x8 af[4];
  #pragma unroll
  for (int s = 0; s < 4; ++s) af[s] = *(const bf16x8*)(Ab + s * 32);

  float bs0[8];
  #pragma unroll
  for (int t = 0; t < 8; ++t) bs0[t] = bias0[t * 16 + colt];

  // ---- pass 0 ----
  {
    const u16* Bb = Bt0 + colt * HD + kq * 8;
    #pragma unroll
    for (int tt = 0; tt < 8; ++tt) {
      f32x4 acc = {0.f, 0.f, 0.f, 0.f};
      #pragma unroll
      for (int s = 0; s < 4; ++s) {
        bf16x8 bf = *(const bf16x8*)(Bb + tt * 16 * HD + s * 32);
        acc = __builtin_amdgcn_mfma_f32_16x16x32_bf16(af[s], bf, acc, 0, 0, 0);
      }
      #pragma unroll
      for (int r = 0; r < 4; ++r)
        myO[(kq * 4 + r) * 136 + tt * 16 + colt] = f2b(acc[r] + bs0[tt]);
    }
    #pragma unroll
    for (int q = 0; q < 4; ++q) {
      int idx = q * 64 + lane;
      int row = idx >> 4, ch = idx & 15;
      uint4 v = *(const uint4*)(myO + row * 136 + ch * 8);
      *(uint4*)(o0 + ((size_t)tile * 16 + row) * HD + ch * 8) = v;
    }
  }
  // ---- pass 1 (conv: second transform, same A) ----
  if (Bt1) {
    float bs1[8];
    #pragma unroll
    for (int t = 0; t < 8; ++t) bs1[t] = bias1[t * 16 + colt];
    const u16* Bb = Bt1 + colt * HD + kq * 8;
    #pragma unroll
    for (int tt = 0; tt < 8; ++tt) {
      f32x4 acc = {0.f, 0.f, 0.f, 0.f};
      #pragma unroll
      for (int s = 0; s < 4; ++s) {
        bf16x8 bf = *(const bf16x8*)(Bb + tt * 16 * HD + s * 32);
        acc = __builtin_amdgcn_mfma_f32_16x16x32_bf16(af[s], bf, acc, 0, 0, 0);
      }
      #pragma unroll
      for (int r = 0; r < 4; ++r)
        myO[(kq * 4 + r) * 136 + tt * 16 + colt] = f2b(acc[r] + bs1[tt]);
    }
    #pragma unroll
    for (int q = 0; q < 4; ++q) {
      int idx = q * 64 + lane;
      int row = idx >> 4, ch = idx & 15;
      uint4 v = *(const uint4*)(myO + row * 136 + ch * 8);
      *(uint4*)(o1 + ((size_t)tile * 16 + row) * HD + ch * 8) = v;
    }
  }
}

// ---- per-channel stats (mean/var inputs) of a bf16 [NN,128] buffer ----
// Thread's channel-pair is fixed (i&63): register accumulation over ~100 rows,
// LDS reduce, 256 atomics/address total (grid=256).
__global__ __launch_bounds__(256) void k_stat(const u16* __restrict__ hb,
                                              float* __restrict__ ssum,
                                              float* __restrict__ ssq) {
  __shared__ float rs0[256], rs1[256], rq0[256], rq1[256];
  int tid = threadIdx.x;
  float s0 = 0.f, s1 = 0.f, q0 = 0.f, q1 = 0.f;
  for (int i = blockIdx.x * 256 + tid; i < NN * 64; i += 256 * 256) {
    u32 xp = ((const u32*)hb)[i];
    float v0 = b2f(xp & 0xFFFFu), v1 = b2f(xp >> 16);
    s0 += v0; q0 += v0 * v0;
    s1 += v1; q1 += v1 * v1;
  }
  rs0[tid] = s0; rs1[tid] = s1; rq0[tid] = q0; rq1[tid] = q1;
  __syncthreads();
  if (tid < 64) {
    float S0 = 0.f, S1 = 0.f, Q0 = 0.f, Q1 = 0.f;
    #pragma unroll
    for (int w = 0; w < 4; ++w) {
      S0 += rs0[tid + 64 * w]; S1 += rs1[tid + 64 * w];
      Q0 += rq0[tid + 64 * w]; Q1 += rq1[tid + 64 * w];
    }
    atomicAdd(&ssum[tid * 2], S0);
    atomicAdd(&ssum[tid * 2 + 1], S1);
    atomicAdd(&ssq[tid * 2], Q0);
    atomicAdd(&ssq[tid * 2 + 1], Q1);
  }
}

// ---- BN + relu apply, bf16 -> bf16 (feeds next layer) ----
__global__ void k_bnrelu(const u16* __restrict__ hb, const float* __restrict__ ssum,
                         const float* __restrict__ ssq, const float* __restrict__ gamma,
                         const float* __restrict__ beta, u16* __restrict__ xo) {
  int i = blockIdx.x * blockDim.x + threadIdx.x;
  if (i >= NN * 64) return;
  int cp = (i & 63) * 2;
  u32 xp = ((const u32*)hb)[i];
  float v0 = b2f(xp & 0xFFFFu), v1 = b2f(xp >> 16);
  const float invn = 1.0f / 100000.0f;
  float mu0 = ssum[cp] * invn, mu1 = ssum[cp + 1] * invn;
  float va0 = fmaxf(ssq[cp] * invn - mu0 * mu0, 0.f);
  float va1 = fmaxf(ssq[cp + 1] * invn - mu1 * mu1, 0.f);
  float s0 = rsqrtf(va0 + 1e-5f) * gamma[cp];
  float s1 = rsqrtf(va1 + 1e-5f) * gamma[cp + 1];
  float o0 = fmaxf((v0 - mu0) * s0 + beta[cp], 0.f);
  float o1 = fmaxf((v1 - mu1) * s1 + beta[cp + 1], 0.f);
  ((u32*)xo)[i] = (u32)f2b(o0) | ((u32)f2b(o1) << 16);
}

// ---- fused edge phase v4 (round-1 winner): 16 lanes/edge, 4 edges/iter ----
// Pinned at ~54 µs by L2-miss (L3/fabric) bandwidth — do not re-attack.
__global__ __launch_bounds__(256) void k_edge4(
    const u16* __restrict__ xs_b, const u16* __restrict__ xd_b,
    const int* __restrict__ row_start, const int* __restrict__ deg,
    const int* __restrict__ ss, const float* __restrict__ att,
    const float* __restrict__ cb, u16* __restrict__ out_b) {
  int dv = blockIdx.x * 4 + (threadIdx.x >> 6);
  if (dv >= NN) return;
  const int lane = threadIdx.x & 63;
  const int cl = lane & 15;
  const int grp = lane >> 4;

  const float L2E = 1.4426950408889634f;
  float4 av0 = *(const float4*)(att + cl * 8);
  float4 av1 = *(const float4*)(att + cl * 8 + 4);
  float al[8] = {av0.x, av0.y, av0.z, av0.w, av1.x, av1.y, av1.z, av1.w};
  f32x2 a6[4], a4[4];
  #pragma unroll
  for (int k = 0; k < 4; ++k) {
    a6[k].x = L2E * 0.6f * al[2 * k];     a6[k].y = L2E * 0.6f * al[2 * k + 1];
    a4[k].x = L2E * 0.4f * al[2 * k];     a4[k].y = L2E * 0.4f * al[2 * k + 1];
  }
  uint4 xdp = *(const uint4*)(xd_b + (size_t)dv * HD + cl * 8);
  u32 xdw[4] = {xdp.x, xdp.y, xdp.z, xdp.w};
  f32x2 xd4[4];
  #pragma unroll
  for (int k = 0; k < 4; ++k) {
    xd4[k].x = __uint_as_float(xdw[k] << 16);
    xd4[k].y = __uint_as_float(xdw[k] & 0xFFFF0000u);
  }

  const int base = row_start[dv];
  const int n = deg[dv];
  f32x2 acc[4] = {{0.f, 0.f}, {0.f, 0.f}, {0.f, 0.f}, {0.f, 0.f}};
  float wsum = 0.f;

  for (int e0 = 0; e0 < n; e0 += 4) {
    int e = e0 + grp;
    int idx = ss[base + ((e < n) ? e : 0)];
    uint4 p = *(const uint4*)(xs_b + (size_t)idx * HD + cl * 8);
    u32 pw[4] = {p.x, p.y, p.z, p.w};
    f32x2 xv[4];
    f32x2 qv = {0.f, 0.f};
    #pragma unroll
    for (int k = 0; k < 4; ++k) {
      f32x2 x2;
      x2.x = __uint_as_float(pw[k] << 16);
      x2.y = __uint_as_float(pw[k] & 0xFFFF0000u);
      xv[k] = x2;
      f32x2 t = x2 + xd4[k];
      f32x2 ab = {__builtin_fabsf(t.x), __builtin_fabsf(t.y)};
      qv += a4[k] * ab;
      qv += a6[k] * t;
    }
    float q = qv.x + qv.y;
    q = dppadd<0xB1>(q);
    q = dppadd<0x4E>(q);
    q = dppadd<0x124>(q);
    q = dppadd<0x128>(q);
    float w = (e < n) ? exp2f(q) : 0.f;
    wsum += w;
    #pragma unroll
    for (int k = 0; k < 4; ++k) acc[k] += xv[k] * w;
  }

  #pragma unroll
  for (int k = 0; k < 4; ++k) {
    acc[k].x += __shfl_xor(acc[k].x, 16, 64);
    acc[k].y += __shfl_xor(acc[k].y, 16, 64);
    acc[k].x += __shfl_xor(acc[k].x, 32, 64);
    acc[k].y += __shfl_xor(acc[k].y, 32, 64);
  }
  wsum += __shfl_xor(wsum, 16, 64);
  wsum += __shfl_xor(wsum, 32, 64);

  if (grp == 0) {
    float inv = 1.f / (wsum + 1e-16f);
    float4 cb0 = *(const float4*)(cb + cl * 8);
    float4 cb1 = *(const float4*)(cb + cl * 8 + 4);
    float cbl[8] = {cb0.x, cb0.y, cb0.z, cb0.w, cb1.x, cb1.y, cb1.z, cb1.w};
    u32 ow[4];
    #pragma unroll
    for (int k = 0; k < 4; ++k) {
      float o0 = acc[k].x * inv + cbl[2 * k];
      float o1 = acc[k].y * inv + cbl[2 * k + 1];
      ow[k] = (u32)f2b(o0) | ((u32)f2b(o1) << 16);
    }
    uint4 o;
    o.x = ow[0]; o.y = ow[1]; o.z = ow[2]; o.w = ow[3];
    *(uint4*)(out_b + (size_t)dv * HD + cl * 8) = o;
  }
}

// ---- final BN apply -> fp32 out ----
__global__ void k_bn(const u16* __restrict__ hb, const float* __restrict__ ssum,
                     const float* __restrict__ ssq, const float* __restrict__ gamma,
                     const float* __restrict__ beta, float* __restrict__ fout) {
  int i = blockIdx.x * blockDim.x + threadIdx.x;
  if (i >= NN * 64) return;
  int cp = (i & 63) * 2;
  u32 xp = ((const u32*)hb)[i];
  float v0 = b2f(xp & 0xFFFFu), v1 = b2f(xp >> 16);
  const float invn = 1.0f / 100000.0f;
  float mu0 = ssum[cp] * invn, mu1 = ssum[cp + 1] * invn;
  float va0 = fmaxf(ssq[cp] * invn - mu0 * mu0, 0.f);
  float va1 = fmaxf(ssq[cp + 1] * invn - mu1 * mu1, 0.f);
  float s0 = rsqrtf(va0 + 1e-5f) * gamma[cp];
  float s1 = rsqrtf(va1 + 1e-5f) * gamma[cp + 1];
  float o0 = (v0 - mu0) * s0 + beta[cp];
  float o1 = (v1 - mu1) * s1 + beta[cp + 1];
  int row = i >> 6;
  *(float2*)(fout + row * 128 + cp) = make_float2(o0, o1);
}

extern "C" void kernel_launch(void* const* d_in, const int* in_sizes, int n_in,
                              void* d_out, int out_size, void* d_ws, size_t ws_size,
                              hipStream_t stream) {
  const float* x    = (const float*)d_in[0];
  const int*   ei   = (const int*)d_in[1];
  const float* Wl   = (const float*)d_in[2];
  const float* bl   = (const float*)d_in[3];
  const float* Wr   = (const float*)d_in[4];
  const float* br   = (const float*)d_in[5];
  const float* att  = (const float*)d_in[6];
  const float* cb   = (const float*)d_in[7];
  const float* Wlin = (const float*)d_in[8];
  const float* blin = (const float*)d_in[9];
  const float* gm   = (const float*)d_in[10];
  const float* bt   = (const float*)d_in[11];
  const int* esrc = ei;
  const int* edst = ei + NE;

  // ws layout
  u16* xb    = (u16*)d_ws;            // layer0 input bf16; reused for relu(BN(h0))
  u16* xs_b  = xb + NN * HD;
  u16* xd_b  = xs_b + NN * HD;
  u16* out_b = xd_b + NN * HD;        // conv out; lin GEMM runs in-place here
  u16* Wt    = out_b + NN * HD;       // 6*16384 bf16
  int* deg       = (int*)(Wt + 6 * 16384);
  int* cnt       = deg + NN;
  int* cursor    = cnt + NN;
  int* row_start = cursor + 1;
  int* srcs      = row_start + NN;    // E ints
  float* ssum0   = (float*)(srcs + NE);
  float* ssq0    = ssum0 + 128;
  float* ssum1   = ssq0 + 128;
  float* ssq1    = ssum1 + 128;

  hipMemsetAsync(deg, 0, (size_t)(2 * NN + 1) * 4, stream);
  hipMemsetAsync(ssum0, 0, 4 * 128 * 4, stream);
  k_init<<<(CAST_N + PREP_N + NE + 255) / 256, 256, 0, stream>>>(
      x, xb, Wl, Wr, Wlin, Wt, edst, deg);
  k_alloc<<<(NN + 255) / 256, 256, 0, stream>>>(deg, row_start, cursor);
  k_fill<<<(NE + 255) / 256, 256, 0, stream>>>(esrc, edst, row_start, cnt, srcs);

  const int gg = (NT + 3) / 4;  // 1563 blocks, 1 tile per wave
  const u16* wt0_l = Wt;             const u16* wt0_r = Wt + 16384;     const u16* wt0_lin = Wt + 2 * 16384;
  const u16* wt1_l = Wt + 3 * 16384; const u16* wt1_r = Wt + 4 * 16384; const u16* wt1_lin = Wt + 5 * 16384;

  // ---- layer 0 ----
  k_gemm7<<<gg, 256, 0, stream>>>(xb, wt0_l, wt0_r, bl, br, xs_b, xd_b);
  k_edge4<<<(NN + 3) / 4, 256, 0, stream>>>(xs_b, xd_b, row_start, deg, srcs,
                                            att, cb, out_b);
  k_gemm7<<<gg, 256, 0, stream>>>(out_b, wt0_lin, nullptr, blin, nullptr,
                                  out_b, nullptr);  // in-place lin
  k_stat<<<256, 256, 0, stream>>>(out_b, ssum0, ssq0);
  k_bnrelu<<<(NN * 64 + 255) / 256, 256, 0, stream>>>(out_b, ssum0, ssq0, gm, bt, xb);
  // ---- layer 1 ----
  k_gemm7<<<gg, 256, 0, stream>>>(xb, wt1_l, wt1_r, bl + 128, br + 128, xs_b, xd_b);
  k_edge4<<<(NN + 3) / 4, 256, 0, stream>>>(xs_b, xd_b, row_start, deg, srcs,
                                            att + 128, cb + 128, out_b);
  k_gemm7<<<gg, 256, 0, stream>>>(out_b, wt1_lin, nullptr, blin + 128, nullptr,
                                  out_b, nullptr);  // in-place lin
  k_stat<<<256, 256, 0, stream>>>(out_b, ssum1, ssq1);
  k_bn<<<(NN * 64 + 255) / 256, 256, 0, stream>>>(out_b, ssum1, ssq1,
                                                  gm + 128, bt + 128, (float*)d_out);
}